// Round 1
// baseline (158.919 us; speedup 1.0000x reference)
//
#include <hip/hip_runtime.h>
#include <hip/hip_bf16.h>

#define BB 16
#define NN 512
#define NH 8
#define DD 64
#define QBLK 64      // q rows per block (4 waves x 16)
#define WAVES 4
#define KBLK 128     // keys per LDS staging chunk
#define NCHUNK 4     // NN / KBLK
#define NT 32        // NN/16 score tiles per wave strip
#define TPC 8        // tiles per chunk (KBLK/16)

typedef __attribute__((ext_vector_type(8))) short bf16x8;
typedef __attribute__((ext_vector_type(4))) float f32x4;

__device__ __forceinline__ unsigned short f2bf(float f) {
    unsigned int u = __float_as_uint(f);
    u += 0x7fffu + ((u >> 16) & 1u);     // round-to-nearest-even
    return (unsigned short)(u >> 16);
}
__device__ __forceinline__ float bf2f(unsigned short h) {
    return __uint_as_float(((unsigned int)h) << 16);
}

// S = 8*(2*QK^T - q2 - k2 + geo); softmax rows; out = W*V.
// Split-bf16 (hi/lo) QK^T for fp32-grade logits; bf16 PV.
__global__ __launch_bounds__(256, 2) void geo_attn_kernel(
    const float* __restrict__ Q, const float* __restrict__ K,
    const float* __restrict__ V, const float* __restrict__ GEO,
    float* __restrict__ OUT)
{
    const int qt  = blockIdx.x;   // 0..7
    const int h   = blockIdx.y;   // 0..7
    const int b   = blockIdx.z;   // 0..15
    const int tid = threadIdx.x;
    const int w    = tid >> 6;
    const int lane = tid & 63;
    const int g = lane >> 4;      // 0..3
    const int c = lane & 15;      // 0..15

    // Region A (32KB), phase-aliased: QK: Khi|Klo ; PV: vT|P
    __shared__ unsigned short smemA[16384];
    __shared__ float k2p[2][NN];
    __shared__ float rowinv[WAVES][16];

    unsigned short* Khi = smemA;                          // [KBLK][64] swizzled
    unsigned short* Klo = smemA + KBLK*DD;
    unsigned short* vT  = smemA;                          // [64][KBLK] swizzled
    unsigned short* Pld = smemA + DD*KBLK + w*16*KBLK;    // [16][KBLK] per wave

    const int qb = qt*QBLK + w*16;

    // ---- Q fragments (hi/lo split) + q2 ----
    // A-frag: lane holds A[row=c][k=g*8+i]; dc selects d-block of 32
    bf16x8 qhi[2], qlo[2];
    float q2v = 0.f;
    {
        const float* qrow = Q + ((size_t)((b*NN + qb + c)*NH + h))*DD;
        #pragma unroll
        for (int dc = 0; dc < 2; ++dc) {
            float buf[8];
            *(float4*)&buf[0] = *(const float4*)(qrow + dc*32 + g*8);
            *(float4*)&buf[4] = *(const float4*)(qrow + dc*32 + g*8 + 4);
            #pragma unroll
            for (int i = 0; i < 8; ++i) {
                float f = buf[i];
                q2v += f*f;
                unsigned short hu = f2bf(f);
                qhi[dc][i] = (short)hu;
                qlo[dc][i] = (short)f2bf(f - bf2f(hu));
            }
        }
    }
    q2v += __shfl_xor(q2v, 16);   // reduce over g: full ||q||^2 per row c
    q2v += __shfl_xor(q2v, 32);

    f32x4 zero4; zero4[0]=0.f; zero4[1]=0.f; zero4[2]=0.f; zero4[3]=0.f;
    f32x4 acc[NT];
    #pragma unroll
    for (int t = 0; t < NT; ++t) acc[t] = zero4;

    // ---- QK^T over key chunks (split-bf16, 3 MFMAs per subtile) ----
    #pragma unroll
    for (int c2 = 0; c2 < NCHUNK; ++c2) {
        __syncthreads();
        {   // stage K chunk -> LDS hi/lo (XOR-swizzled), plus k2 partials
            const int keyl = tid & (KBLK-1);
            const int half = tid >> 7;
            const int d0 = half*32;
            const float* krow = K + ((size_t)((b*NN + c2*KBLK + keyl)*NH + h))*DD + d0;
            float k2s = 0.f;
            #pragma unroll
            for (int jj = 0; jj < 8; ++jj) {
                float4 f4 = *(const float4*)(krow + jj*4);
                float fb[4] = {f4.x, f4.y, f4.z, f4.w};
                unsigned short hu[4], lu[4];
                #pragma unroll
                for (int e = 0; e < 4; ++e) {
                    float f = fb[e];
                    k2s += f*f;
                    hu[e] = f2bf(f);
                    lu[e] = f2bf(f - bf2f(hu[e]));
                }
                int idx = (keyl*DD + d0 + jj*4) ^ ((keyl & 7) << 3);
                *(uint2*)&Khi[idx] = make_uint2((unsigned)hu[0] | ((unsigned)hu[1] << 16),
                                                (unsigned)hu[2] | ((unsigned)hu[3] << 16));
                *(uint2*)&Klo[idx] = make_uint2((unsigned)lu[0] | ((unsigned)lu[1] << 16),
                                                (unsigned)lu[2] | ((unsigned)lu[3] << 16));
            }
            k2p[half][c2*KBLK + keyl] = k2s;
        }
        __syncthreads();
        #pragma unroll
        for (int tl = 0; tl < TPC; ++tl) {
            const int key = tl*16 + c;   // B-frag col = key
            #pragma unroll
            for (int dc = 0; dc < 2; ++dc) {
                int idx = (key*DD + dc*32 + g*8) ^ ((key & 7) << 3);
                bf16x8 kh = *(const bf16x8*)&Khi[idx];
                bf16x8 kl = *(const bf16x8*)&Klo[idx];
                acc[c2*TPC+tl] = __builtin_amdgcn_mfma_f32_16x16x32_bf16(qhi[dc], kh, acc[c2*TPC+tl], 0,0,0);
                acc[c2*TPC+tl] = __builtin_amdgcn_mfma_f32_16x16x32_bf16(qlo[dc], kh, acc[c2*TPC+tl], 0,0,0);
                acc[c2*TPC+tl] = __builtin_amdgcn_mfma_f32_16x16x32_bf16(qhi[dc], kl, acc[c2*TPC+tl], 0,0,0);
            }
        }
    }

    // ---- softmax; scores in D-layout: S[q=4g+r][key=16t+c] ----
    float nq2[4];
    #pragma unroll
    for (int r = 0; r < 4; ++r) nq2[r] = -8.f * __shfl(q2v, g*4 + r);

    const float* geoB = GEO + (size_t)b*NN*NN + (size_t)(qb + 4*g)*NN;

    float mx[4] = {-3e38f, -3e38f, -3e38f, -3e38f};
    #pragma unroll
    for (int t = 0; t < NT; ++t) {
        float kk8 = -8.f * (k2p[0][t*16 + c] + k2p[1][t*16 + c]);
        #pragma unroll
        for (int r = 0; r < 4; ++r) {
            float gv = geoB[(size_t)r*NN + t*16 + c];
            float s = fmaf(16.f, acc[t][r], fmaf(8.f, gv, nq2[r] + kk8));
            acc[t][r] = s;
            mx[r] = fmaxf(mx[r], s);
        }
    }
    #pragma unroll
    for (int r = 0; r < 4; ++r) {
        float mv = mx[r];
        mv = fmaxf(mv, __shfl_xor(mv, 1));
        mv = fmaxf(mv, __shfl_xor(mv, 2));
        mv = fmaxf(mv, __shfl_xor(mv, 4));
        mv = fmaxf(mv, __shfl_xor(mv, 8));
        mx[r] = mv;
    }
    float sm[4] = {0.f, 0.f, 0.f, 0.f};
    #pragma unroll
    for (int t = 0; t < NT; ++t) {
        #pragma unroll
        for (int r = 0; r < 4; ++r) {
            float p = __expf(acc[t][r] - mx[r]);
            acc[t][r] = p;                       // keep unnormalized P in regs
            sm[r] += p;
        }
    }
    #pragma unroll
    for (int r = 0; r < 4; ++r) {
        float sv = sm[r];
        sv += __shfl_xor(sv, 1);
        sv += __shfl_xor(sv, 2);
        sv += __shfl_xor(sv, 4);
        sv += __shfl_xor(sv, 8);
        sm[r] = sv;
    }
    if (c == 0) {
        #pragma unroll
        for (int r = 0; r < 4; ++r) rowinv[w][4*g + r] = 1.f / sm[r];
    }

    // ---- PV (swapped: out^T = V^T * P^T -> float4 epilogue) ----
    f32x4 oacc[4];
    #pragma unroll
    for (int cb = 0; cb < 4; ++cb) oacc[cb] = zero4;

    #pragma unroll
    for (int c2 = 0; c2 < NCHUNK; ++c2) {
        __syncthreads();
        {   // stage V^T chunk: vT[d][key] bf16, XOR-swizzled rows
            const int keyl = tid & (KBLK-1);
            const int half = tid >> 7;
            const int d0 = half*32;
            const float* vrow = V + ((size_t)((b*NN + c2*KBLK + keyl)*NH + h))*DD + d0;
            #pragma unroll
            for (int jj = 0; jj < 8; ++jj) {
                float4 f4 = *(const float4*)(vrow + jj*4);
                float fb[4] = {f4.x, f4.y, f4.z, f4.w};
                #pragma unroll
                for (int e = 0; e < 4; ++e) {
                    int d = d0 + jj*4 + e;
                    vT[(d*KBLK + keyl) ^ ((d & 7) << 3)] = f2bf(fb[e]);
                }
            }
        }
        // write this chunk's P (own wave section), bf16
        #pragma unroll
        for (int tl = 0; tl < TPC; ++tl) {
            #pragma unroll
            for (int r = 0; r < 4; ++r) {
                int qloc = 4*g + r;
                Pld[(qloc*KBLK + tl*16 + c) ^ ((qloc & 7) << 3)] = f2bf(acc[c2*TPC+tl][r]);
            }
        }
        __syncthreads();
        #pragma unroll
        for (int kc = 0; kc < 4; ++kc) {
            int kb2 = kc*32 + g*8;
            // B-frag: B[k=key][col=q] = P[q=c][key]
            bf16x8 pf = *(const bf16x8*)&Pld[(c*KBLK + kb2) ^ ((c & 7) << 3)];
            #pragma unroll
            for (int cb = 0; cb < 4; ++cb) {
                int d = cb*16 + c;   // A-frag: A[row=d][k=key]
                bf16x8 vf = *(const bf16x8*)&vT[(d*KBLK + kb2) ^ ((d & 7) << 3)];
                oacc[cb] = __builtin_amdgcn_mfma_f32_16x16x32_bf16(vf, pf, oacc[cb], 0,0,0);
            }
        }
    }

    // out^T D-layout: row=d=cb*16+4g+r, col=q=c -> float4 stores
    const float inv = rowinv[w][c];
    float* orow = OUT + ((size_t)((b*NN + qb + c)*NH + h))*DD + 4*g;
    #pragma unroll
    for (int cb = 0; cb < 4; ++cb) {
        float4 ov;
        ov.x = oacc[cb][0] * inv;
        ov.y = oacc[cb][1] * inv;
        ov.z = oacc[cb][2] * inv;
        ov.w = oacc[cb][3] * inv;
        *(float4*)(orow + cb*16) = ov;
    }
}

extern "C" void kernel_launch(void* const* d_in, const int* in_sizes, int n_in,
                              void* d_out, int out_size, void* d_ws, size_t ws_size,
                              hipStream_t stream) {
    const float* q   = (const float*)d_in[0];
    const float* k   = (const float*)d_in[1];
    const float* v   = (const float*)d_in[2];
    const float* geo = (const float*)d_in[3];
    float* out = (float*)d_out;
    dim3 grid(NN/QBLK, NH, BB);   // (8, 8, 16) = 1024 blocks
    geo_attn_kernel<<<grid, 256, 0, stream>>>(q, k, v, geo, out);
}

// Round 2
// 154.415 us; speedup vs baseline: 1.0292x; 1.0292x over previous
//
#include <hip/hip_runtime.h>
#include <hip/hip_bf16.h>

#define BB 16
#define NN 512
#define NH 8
#define DD 64
#define QBLK 64      // q rows per block (4 waves x 16)
#define WAVES 4
// flash main kernel chunking
#define CK 64        // keys per chunk
#define NCH 8        // NN / CK
#define TL 4         // 16-key tiles per chunk
// fallback kernel chunking (round-1)
#define KBLK 128
#define NCHUNK 4
#define NT 32
#define TPC 8

typedef __attribute__((ext_vector_type(8))) short bf16x8;
typedef __attribute__((ext_vector_type(4))) float f32x4;

__device__ __forceinline__ unsigned short f2bf(float f) {
    unsigned int u = __float_as_uint(f);
    u += 0x7fffu + ((u >> 16) & 1u);     // round-to-nearest-even
    return (unsigned short)(u >> 16);
}
__device__ __forceinline__ float bf2f(unsigned short h) {
    return __uint_as_float(((unsigned int)h) << 16);
}
// async global->LDS, 16B per lane; lds must be wave-uniform base (dest = base + lane*16)
__device__ __forceinline__ void gload16(const void* gsrc, void* lds) {
    __builtin_amdgcn_global_load_lds(
        (const __attribute__((address_space(1))) unsigned int*)gsrc,
        (__attribute__((address_space(3))) unsigned int*)lds, 16, 0, 0);
}

// ---------------- prep: K -> (hi,lo) bf16 swizzled images, V -> V^T bf16 swizzled image, k2 ----------------
// Khi/Klo image per (b,h): elem pos = (key*64 + d) ^ ((key&7)<<3)   [chunks of 64 keys are 8KB contiguous]
// Vt  image per (b,h,chunk): pos = (d*64 + kl) ^ ((d&7)<<3)
__global__ __launch_bounds__(256) void geo_prep(
    const float* __restrict__ K, const float* __restrict__ V,
    unsigned short* __restrict__ KhiG, unsigned short* __restrict__ KloG,
    unsigned short* __restrict__ VtG, float* __restrict__ k2G)
{
    const int c2 = blockIdx.x;   // 0..7 key chunk
    const int h  = blockIdx.y;
    const int b  = blockIdx.z;
    const int bh = b*NH + h;
    const int tid = threadIdx.x;
    const int lane16 = tid & 15;
    const int grp    = tid >> 4;   // 0..15

    __shared__ unsigned short Vl[DD*66];   // [d][kl], stride 66 to break banks

    const size_t kbase = (size_t)bh*(NN*DD) + (size_t)c2*(CK*DD);
    #pragma unroll
    for (int kk = 0; kk < 4; ++kk) {
        const int kl = kk*16 + grp;
        const float* krow = K + ((size_t)(((b*NN + c2*CK + kl)*NH) + h))*DD + lane16*4;
        const float* vrow = V + ((size_t)(((b*NN + c2*CK + kl)*NH) + h))*DD + lane16*4;
        float4 kf = *(const float4*)krow;
        float4 vf = *(const float4*)vrow;
        float fb[4] = {kf.x, kf.y, kf.z, kf.w};
        float vb[4] = {vf.x, vf.y, vf.z, vf.w};
        unsigned short hu[4], lu[4];
        float k2s = 0.f;
        #pragma unroll
        for (int e = 0; e < 4; ++e) {
            float f = fb[e];
            k2s += f*f;
            hu[e] = f2bf(f);
            lu[e] = f2bf(f - bf2f(hu[e]));
            Vl[(lane16*4 + e)*66 + kl] = f2bf(vb[e]);
        }
        k2s += __shfl_xor(k2s, 1);
        k2s += __shfl_xor(k2s, 2);
        k2s += __shfl_xor(k2s, 4);
        k2s += __shfl_xor(k2s, 8);
        if (lane16 == 0) k2G[bh*NN + c2*CK + kl] = k2s;
        const int pos = (kl*DD + lane16*4) ^ ((kl & 7) << 3);
        *(uint2*)&KhiG[kbase + pos] = make_uint2((unsigned)hu[0] | ((unsigned)hu[1] << 16),
                                                 (unsigned)hu[2] | ((unsigned)hu[3] << 16));
        *(uint2*)&KloG[kbase + pos] = make_uint2((unsigned)lu[0] | ((unsigned)lu[1] << 16),
                                                 (unsigned)lu[2] | ((unsigned)lu[3] << 16));
    }
    __syncthreads();
    const size_t vbase = ((size_t)bh*NCH + c2)*(DD*CK);
    #pragma unroll
    for (int i = 0; i < 4; ++i) {
        const int gi = tid + 256*i;       // 0..1023 8B-granules
        const int d   = gi >> 4;
        const int kl4 = (gi & 15) * 4;
        unsigned short e0 = Vl[d*66 + kl4+0];
        unsigned short e1 = Vl[d*66 + kl4+1];
        unsigned short e2 = Vl[d*66 + kl4+2];
        unsigned short e3 = Vl[d*66 + kl4+3];
        const int pos = (d*CK + kl4) ^ ((d & 7) << 3);
        *(uint2*)&VtG[vbase + pos] = make_uint2((unsigned)e0 | ((unsigned)e1 << 16),
                                                (unsigned)e2 | ((unsigned)e3 << 16));
    }
}

// ---------------- main: flash-style online softmax, DMA staging ----------------
__global__ __launch_bounds__(256, 3) void geo_attn_main(
    const float* __restrict__ Q, const float* __restrict__ GEO,
    const unsigned short* __restrict__ KhiG, const unsigned short* __restrict__ KloG,
    const unsigned short* __restrict__ VtG, const float* __restrict__ k2G,
    float* __restrict__ OUT)
{
    const int qt  = blockIdx.x;
    const int h   = blockIdx.y;
    const int b   = blockIdx.z;
    const int bh  = b*NH + h;
    const int tid = threadIdx.x;
    const int w    = tid >> 6;
    const int lane = tid & 63;
    const int g = lane >> 4;
    const int c = lane & 15;

    __shared__ unsigned short Khi[CK*DD];        // 8KB
    __shared__ unsigned short Klo[CK*DD];        // 8KB
    __shared__ unsigned short vT [DD*CK];        // 8KB
    __shared__ float geoS[QBLK*CK];              // 16KB (granule-swizzled)
    __shared__ unsigned short Pld[WAVES*16*CK];  // 8KB
    __shared__ float k2s[NN];                    // 2KB
    __shared__ float sRow[WAVES][16];
    __shared__ float rowinv[WAVES][16];

    if (tid < 128) *(float4*)&k2s[tid*4] = *(const float4*)&k2G[(size_t)bh*NN + tid*4];

    const int qb = qt*QBLK + w*16;

    // Q fragments (hi/lo split) + q2
    bf16x8 qhi[2], qlo[2];
    float q2v = 0.f;
    {
        const float* qrow = Q + ((size_t)((b*NN + qb + c)*NH + h))*DD;
        #pragma unroll
        for (int dc = 0; dc < 2; ++dc) {
            float buf[8];
            *(float4*)&buf[0] = *(const float4*)(qrow + dc*32 + g*8);
            *(float4*)&buf[4] = *(const float4*)(qrow + dc*32 + g*8 + 4);
            #pragma unroll
            for (int i = 0; i < 8; ++i) {
                float f = buf[i];
                q2v += f*f;
                unsigned short hu = f2bf(f);
                qhi[dc][i] = (short)hu;
                qlo[dc][i] = (short)f2bf(f - bf2f(hu));
            }
        }
    }
    q2v += __shfl_xor(q2v, 16);
    q2v += __shfl_xor(q2v, 32);
    float nq2[4];
    #pragma unroll
    for (int r = 0; r < 4; ++r) nq2[r] = -8.f * __shfl(q2v, g*4 + r);

    f32x4 oacc[4];
    #pragma unroll
    for (int cb = 0; cb < 4; ++cb) { oacc[cb][0]=0.f; oacc[cb][1]=0.f; oacc[cb][2]=0.f; oacc[cb][3]=0.f; }
    float m_r[4] = {-3e38f, -3e38f, -3e38f, -3e38f};
    float l_r[4] = {0.f, 0.f, 0.f, 0.f};

    const char* gKhiB = (const char*)KhiG + (size_t)bh*(NN*DD*2);
    const char* gKloB = (const char*)KloG + (size_t)bh*(NN*DD*2);
    const char* gVtB  = (const char*)VtG  + (size_t)bh*(NN*DD*2);
    const float* geoQ = GEO + (size_t)b*NN*NN + (size_t)(qt*QBLK)*NN;

    for (int ch = 0; ch < NCH; ++ch) {
        __syncthreads();   // previous chunk fully consumed
        {
            const char* srcKhi = gKhiB + ch*(CK*DD*2);
            const char* srcKlo = gKloB + ch*(CK*DD*2);
            const char* srcVt  = gVtB  + ch*(CK*DD*2);
            #pragma unroll
            for (int i = 0; i < 2; ++i) {
                const int off = (w*2 + i)*1024;
                gload16(srcKhi + off + (lane<<4), (char*)Khi + off);
                gload16(srcKlo + off + (lane<<4), (char*)Klo + off);
                gload16(srcVt  + off + (lane<<4), (char*)vT  + off);
            }
            // geo chunk [64 rows][64 cols] f32; 16B-granule swizzle applied on SOURCE side
            #pragma unroll
            for (int i = 0; i < 4; ++i) {
                const int seg = w*4 + i;
                const int row = seg*4 + (lane >> 4);
                const int cg  = (lane & 15) ^ (row & 7);
                gload16((const void*)(geoQ + (size_t)row*NN + ch*CK + cg*4),
                        (char*)geoS + seg*1024);
            }
        }
        __syncthreads();   // staged data ready (vmcnt drained by barrier)

        // QK^T for this chunk (split bf16: 3 MFMAs per subtile)
        f32x4 sacc[TL];
        #pragma unroll
        for (int tl = 0; tl < TL; ++tl) { sacc[tl][0]=0.f; sacc[tl][1]=0.f; sacc[tl][2]=0.f; sacc[tl][3]=0.f; }
        #pragma unroll
        for (int tl = 0; tl < TL; ++tl) {
            const int key = tl*16 + c;
            #pragma unroll
            for (int dc = 0; dc < 2; ++dc) {
                const int idx = (key*DD + dc*32 + g*8) ^ ((key & 7) << 3);
                bf16x8 kh = *(const bf16x8*)&Khi[idx];
                bf16x8 kl = *(const bf16x8*)&Klo[idx];
                sacc[tl] = __builtin_amdgcn_mfma_f32_16x16x32_bf16(qhi[dc], kh, sacc[tl], 0,0,0);
                sacc[tl] = __builtin_amdgcn_mfma_f32_16x16x32_bf16(qlo[dc], kh, sacc[tl], 0,0,0);
                sacc[tl] = __builtin_amdgcn_mfma_f32_16x16x32_bf16(qhi[dc], kl, sacc[tl], 0,0,0);
            }
        }

        // logits + online softmax update
        const int row_base = w*16 + 4*g;
        float cmax[4] = {-3e38f, -3e38f, -3e38f, -3e38f};
        #pragma unroll
        for (int tl = 0; tl < TL; ++tl) {
            const float kk8 = -8.f * k2s[ch*CK + tl*16 + c];
            #pragma unroll
            for (int r = 0; r < 4; ++r) {
                const int rl = row_base + r;
                const float gv = geoS[(rl*16 + ((tl*4 + (c>>2)) ^ (rl & 7)))*4 + (c & 3)];
                float s = fmaf(16.f, sacc[tl][r], fmaf(8.f, gv, nq2[r] + kk8));
                sacc[tl][r] = s;
                cmax[r] = fmaxf(cmax[r], s);
            }
        }
        float fac[4];
        #pragma unroll
        for (int r = 0; r < 4; ++r) {
            float mv = cmax[r];
            mv = fmaxf(mv, __shfl_xor(mv, 1));
            mv = fmaxf(mv, __shfl_xor(mv, 2));
            mv = fmaxf(mv, __shfl_xor(mv, 4));
            mv = fmaxf(mv, __shfl_xor(mv, 8));
            const float mnew = fmaxf(m_r[r], mv);
            fac[r] = __expf(m_r[r] - mnew);
            m_r[r] = mnew;
        }
        if (c == 0) {
            #pragma unroll
            for (int r = 0; r < 4; ++r) sRow[w][4*g + r] = fac[r];
        }
        #pragma unroll
        for (int r = 0; r < 4; ++r) l_r[r] *= fac[r];
        #pragma unroll
        for (int tl = 0; tl < TL; ++tl) {
            #pragma unroll
            for (int r = 0; r < 4; ++r) {
                float p = __expf(sacc[tl][r] - m_r[r]);
                l_r[r] += p;
                const int qloc = 4*g + r;
                Pld[(((w*16 + qloc)*CK) + tl*16 + c) ^ ((qloc & 7) << 3)] = f2bf(p);
            }
        }
        __syncthreads();   // P + sRow visible; all geo reads done

        // PV accumulate (swapped: out^T = V^T * P^T)
        const float sc = sRow[w][c];
        #pragma unroll
        for (int cb = 0; cb < 4; ++cb) {
            oacc[cb][0] *= sc; oacc[cb][1] *= sc; oacc[cb][2] *= sc; oacc[cb][3] *= sc;
        }
        #pragma unroll
        for (int kc = 0; kc < 2; ++kc) {
            bf16x8 pf = *(const bf16x8*)&Pld[(((w*16 + c)*CK) + kc*32 + g*8) ^ ((c & 7) << 3)];
            #pragma unroll
            for (int cb = 0; cb < 4; ++cb) {
                const int d = cb*16 + c;
                bf16x8 vfr = *(const bf16x8*)&vT[(d*CK + kc*32 + g*8) ^ ((d & 7) << 3)];
                oacc[cb] = __builtin_amdgcn_mfma_f32_16x16x32_bf16(vfr, pf, oacc[cb], 0,0,0);
            }
        }
    }

    // epilogue: normalize + store (out^T D-layout -> float4 stores)
    #pragma unroll
    for (int r = 0; r < 4; ++r) {
        float sv = l_r[r];
        sv += __shfl_xor(sv, 1);
        sv += __shfl_xor(sv, 2);
        sv += __shfl_xor(sv, 4);
        sv += __shfl_xor(sv, 8);
        if (c == 0) rowinv[w][4*g + r] = 1.f / sv;
    }
    __syncthreads();
    const float inv = rowinv[w][c];
    float* orow = OUT + ((size_t)((b*NN + qb + c)*NH + h))*DD + 4*g;
    #pragma unroll
    for (int cb = 0; cb < 4; ++cb) {
        float4 ov;
        ov.x = oacc[cb][0] * inv;
        ov.y = oacc[cb][1] * inv;
        ov.z = oacc[cb][2] * inv;
        ov.w = oacc[cb][3] * inv;
        *(float4*)(orow + cb*16) = ov;
    }
}

// ---------------- fallback (round-1 kernel, used if ws too small) ----------------
__global__ __launch_bounds__(256, 2) void geo_attn_fallback(
    const float* __restrict__ Q, const float* __restrict__ K,
    const float* __restrict__ V, const float* __restrict__ GEO,
    float* __restrict__ OUT)
{
    const int qt  = blockIdx.x;
    const int h   = blockIdx.y;
    const int b   = blockIdx.z;
    const int tid = threadIdx.x;
    const int w    = tid >> 6;
    const int lane = tid & 63;
    const int g = lane >> 4;
    const int c = lane & 15;

    __shared__ unsigned short smemA[16384];
    __shared__ float k2p[2][NN];
    __shared__ float rowinvF[WAVES][16];

    unsigned short* KhiF = smemA;
    unsigned short* KloF = smemA + KBLK*DD;
    unsigned short* vTF  = smemA;
    unsigned short* PldF = smemA + DD*KBLK + w*16*KBLK;

    const int qb = qt*QBLK + w*16;

    bf16x8 qhi[2], qlo[2];
    float q2v = 0.f;
    {
        const float* qrow = Q + ((size_t)((b*NN + qb + c)*NH + h))*DD;
        #pragma unroll
        for (int dc = 0; dc < 2; ++dc) {
            float buf[8];
            *(float4*)&buf[0] = *(const float4*)(qrow + dc*32 + g*8);
            *(float4*)&buf[4] = *(const float4*)(qrow + dc*32 + g*8 + 4);
            #pragma unroll
            for (int i = 0; i < 8; ++i) {
                float f = buf[i];
                q2v += f*f;
                unsigned short hu = f2bf(f);
                qhi[dc][i] = (short)hu;
                qlo[dc][i] = (short)f2bf(f - bf2f(hu));
            }
        }
    }
    q2v += __shfl_xor(q2v, 16);
    q2v += __shfl_xor(q2v, 32);

    f32x4 zero4; zero4[0]=0.f; zero4[1]=0.f; zero4[2]=0.f; zero4[3]=0.f;
    f32x4 acc[NT];
    #pragma unroll
    for (int t = 0; t < NT; ++t) acc[t] = zero4;

    #pragma unroll
    for (int c2 = 0; c2 < NCHUNK; ++c2) {
        __syncthreads();
        {
            const int keyl = tid & (KBLK-1);
            const int half = tid >> 7;
            const int d0 = half*32;
            const float* krow = K + ((size_t)((b*NN + c2*KBLK + keyl)*NH + h))*DD + d0;
            float k2sv = 0.f;
            #pragma unroll
            for (int jj = 0; jj < 8; ++jj) {
                float4 f4 = *(const float4*)(krow + jj*4);
                float fb[4] = {f4.x, f4.y, f4.z, f4.w};
                unsigned short hu[4], lu[4];
                #pragma unroll
                for (int e = 0; e < 4; ++e) {
                    float f = fb[e];
                    k2sv += f*f;
                    hu[e] = f2bf(f);
                    lu[e] = f2bf(f - bf2f(hu[e]));
                }
                int idx = (keyl*DD + d0 + jj*4) ^ ((keyl & 7) << 3);
                *(uint2*)&KhiF[idx] = make_uint2((unsigned)hu[0] | ((unsigned)hu[1] << 16),
                                                 (unsigned)hu[2] | ((unsigned)hu[3] << 16));
                *(uint2*)&KloF[idx] = make_uint2((unsigned)lu[0] | ((unsigned)lu[1] << 16),
                                                 (unsigned)lu[2] | ((unsigned)lu[3] << 16));
            }
            k2p[half][c2*KBLK + keyl] = k2sv;
        }
        __syncthreads();
        #pragma unroll
        for (int tl = 0; tl < TPC; ++tl) {
            const int key = tl*16 + c;
            #pragma unroll
            for (int dc = 0; dc < 2; ++dc) {
                int idx = (key*DD + dc*32 + g*8) ^ ((key & 7) << 3);
                bf16x8 kh = *(const bf16x8*)&KhiF[idx];
                bf16x8 kl = *(const bf16x8*)&KloF[idx];
                acc[c2*TPC+tl] = __builtin_amdgcn_mfma_f32_16x16x32_bf16(qhi[dc], kh, acc[c2*TPC+tl], 0,0,0);
                acc[c2*TPC+tl] = __builtin_amdgcn_mfma_f32_16x16x32_bf16(qlo[dc], kh, acc[c2*TPC+tl], 0,0,0);
                acc[c2*TPC+tl] = __builtin_amdgcn_mfma_f32_16x16x32_bf16(qhi[dc], kl, acc[c2*TPC+tl], 0,0,0);
            }
        }
    }

    float nq2[4];
    #pragma unroll
    for (int r = 0; r < 4; ++r) nq2[r] = -8.f * __shfl(q2v, g*4 + r);

    const float* geoB = GEO + (size_t)b*NN*NN + (size_t)(qb + 4*g)*NN;

    float mx[4] = {-3e38f, -3e38f, -3e38f, -3e38f};
    #pragma unroll
    for (int t = 0; t < NT; ++t) {
        float kk8 = -8.f * (k2p[0][t*16 + c] + k2p[1][t*16 + c]);
        #pragma unroll
        for (int r = 0; r < 4; ++r) {
            float gv = geoB[(size_t)r*NN + t*16 + c];
            float s = fmaf(16.f, acc[t][r], fmaf(8.f, gv, nq2[r] + kk8));
            acc[t][r] = s;
            mx[r] = fmaxf(mx[r], s);
        }
    }
    #pragma unroll
    for (int r = 0; r < 4; ++r) {
        float mv = mx[r];
        mv = fmaxf(mv, __shfl_xor(mv, 1));
        mv = fmaxf(mv, __shfl_xor(mv, 2));
        mv = fmaxf(mv, __shfl_xor(mv, 4));
        mv = fmaxf(mv, __shfl_xor(mv, 8));
        mx[r] = mv;
    }
    float sm[4] = {0.f, 0.f, 0.f, 0.f};
    #pragma unroll
    for (int t = 0; t < NT; ++t) {
        #pragma unroll
        for (int r = 0; r < 4; ++r) {
            float p = __expf(acc[t][r] - mx[r]);
            acc[t][r] = p;
            sm[r] += p;
        }
    }
    #pragma unroll
    for (int r = 0; r < 4; ++r) {
        float sv = sm[r];
        sv += __shfl_xor(sv, 1);
        sv += __shfl_xor(sv, 2);
        sv += __shfl_xor(sv, 4);
        sv += __shfl_xor(sv, 8);
        sm[r] = sv;
    }
    if (c == 0) {
        #pragma unroll
        for (int r = 0; r < 4; ++r) rowinvF[w][4*g + r] = 1.f / sm[r];
    }

    f32x4 oacc[4];
    #pragma unroll
    for (int cb = 0; cb < 4; ++cb) oacc[cb] = zero4;

    #pragma unroll
    for (int c2 = 0; c2 < NCHUNK; ++c2) {
        __syncthreads();
        {
            const int keyl = tid & (KBLK-1);
            const int half = tid >> 7;
            const int d0 = half*32;
            const float* vrow = V + ((size_t)((b*NN + c2*KBLK + keyl)*NH + h))*DD + d0;
            #pragma unroll
            for (int jj = 0; jj < 8; ++jj) {
                float4 f4 = *(const float4*)(vrow + jj*4);
                float fb[4] = {f4.x, f4.y, f4.z, f4.w};
                #pragma unroll
                for (int e = 0; e < 4; ++e) {
                    int d = d0 + jj*4 + e;
                    vTF[(d*KBLK + keyl) ^ ((d & 7) << 3)] = f2bf(fb[e]);
                }
            }
        }
        #pragma unroll
        for (int tl = 0; tl < TPC; ++tl) {
            #pragma unroll
            for (int r = 0; r < 4; ++r) {
                int qloc = 4*g + r;
                PldF[(qloc*KBLK + tl*16 + c) ^ ((qloc & 7) << 3)] = f2bf(acc[c2*TPC+tl][r]);
            }
        }
        __syncthreads();
        #pragma unroll
        for (int kc = 0; kc < 4; ++kc) {
            int kb2 = kc*32 + g*8;
            bf16x8 pf = *(const bf16x8*)&PldF[(c*KBLK + kb2) ^ ((c & 7) << 3)];
            #pragma unroll
            for (int cb = 0; cb < 4; ++cb) {
                int d = cb*16 + c;
                bf16x8 vf = *(const bf16x8*)&vTF[(d*KBLK + kb2) ^ ((d & 7) << 3)];
                oacc[cb] = __builtin_amdgcn_mfma_f32_16x16x32_bf16(vf, pf, oacc[cb], 0,0,0);
            }
        }
    }

    const float inv = rowinvF[w][c];
    float* orow = OUT + ((size_t)((b*NN + qb + c)*NH + h))*DD + 4*g;
    #pragma unroll
    for (int cb = 0; cb < 4; ++cb) {
        float4 ov;
        ov.x = oacc[cb][0] * inv;
        ov.y = oacc[cb][1] * inv;
        ov.z = oacc[cb][2] * inv;
        ov.w = oacc[cb][3] * inv;
        *(float4*)(orow + cb*16) = ov;
    }
}

extern "C" void kernel_launch(void* const* d_in, const int* in_sizes, int n_in,
                              void* d_out, int out_size, void* d_ws, size_t ws_size,
                              hipStream_t stream) {
    const float* q   = (const float*)d_in[0];
    const float* k   = (const float*)d_in[1];
    const float* v   = (const float*)d_in[2];
    const float* geo = (const float*)d_in[3];
    float* out = (float*)d_out;

    const size_t IMG = (size_t)BB*NH*NN*DD*2;   // 8,388,608 B per bf16 image
    const size_t need = 3*IMG + (size_t)BB*NH*NN*4;

    if (ws_size >= need) {
        unsigned short* KhiG = (unsigned short*)d_ws;
        unsigned short* KloG = (unsigned short*)((char*)d_ws + IMG);
        unsigned short* VtG  = (unsigned short*)((char*)d_ws + 2*IMG);
        float*          k2G  = (float*)((char*)d_ws + 3*IMG);
        dim3 pgrid(NCH, NH, BB);
        geo_prep<<<pgrid, 256, 0, stream>>>(k, v, KhiG, KloG, VtG, k2G);
        dim3 grid(NN/QBLK, NH, BB);
        geo_attn_main<<<grid, 256, 0, stream>>>(q, geo, KhiG, KloG, VtG, k2G, out);
    } else {
        dim3 grid(NN/QBLK, NH, BB);
        geo_attn_fallback<<<grid, 256, 0, stream>>>(q, k, v, geo, out);
    }
}

// Round 3
// 144.103 us; speedup vs baseline: 1.1028x; 1.0716x over previous
//
#include <hip/hip_runtime.h>
#include <hip/hip_bf16.h>

#define BB 16
#define NN 512
#define NH 8
#define DD 64
#define CK 64        // keys per chunk
#define NCH 8        // NN / CK
#define TL 4         // 16-key tiles per chunk
// main kernel
#define MWAVES 8
#define MQBLK 128    // q rows per block (8 waves x 16)
// fallback kernel (round-1)
#define QBLK 64
#define WAVES 4
#define KBLK 128
#define NCHUNK 4
#define NT 32
#define TPC 8

typedef __attribute__((ext_vector_type(8))) short bf16x8;
typedef __attribute__((ext_vector_type(4))) float f32x4;

__device__ __forceinline__ unsigned short f2bf(float f) {
    unsigned int u = __float_as_uint(f);
    u += 0x7fffu + ((u >> 16) & 1u);     // round-to-nearest-even
    return (unsigned short)(u >> 16);
}
__device__ __forceinline__ float bf2f(unsigned short h) {
    return __uint_as_float(((unsigned int)h) << 16);
}
// async global->LDS, 16B per lane; LDS dest = wave-uniform base + lane*16
__device__ __forceinline__ void gload16(const void* gsrc, void* lds) {
    __builtin_amdgcn_global_load_lds(
        (const __attribute__((address_space(1))) unsigned int*)gsrc,
        (__attribute__((address_space(3))) unsigned int*)lds, 16, 0, 0);
}

// ---------------- prep: K -> (hi,lo) bf16 swizzled images, V -> V^T bf16 swizzled image, k2 ----------------
__global__ __launch_bounds__(256) void geo_prep(
    const float* __restrict__ K, const float* __restrict__ V,
    unsigned short* __restrict__ KhiG, unsigned short* __restrict__ KloG,
    unsigned short* __restrict__ VtG, float* __restrict__ k2G)
{
    const int c2 = blockIdx.x;   // 0..7 key chunk
    const int h  = blockIdx.y;
    const int b  = blockIdx.z;
    const int bh = b*NH + h;
    const int tid = threadIdx.x;
    const int lane16 = tid & 15;
    const int grp    = tid >> 4;   // 0..15

    __shared__ unsigned short Vl[DD*66];

    const size_t kbase = (size_t)bh*(NN*DD) + (size_t)c2*(CK*DD);
    #pragma unroll
    for (int kk = 0; kk < 4; ++kk) {
        const int kl = kk*16 + grp;
        const float* krow = K + ((size_t)(((b*NN + c2*CK + kl)*NH) + h))*DD + lane16*4;
        const float* vrow = V + ((size_t)(((b*NN + c2*CK + kl)*NH) + h))*DD + lane16*4;
        float4 kf = *(const float4*)krow;
        float4 vf = *(const float4*)vrow;
        float fb[4] = {kf.x, kf.y, kf.z, kf.w};
        float vb[4] = {vf.x, vf.y, vf.z, vf.w};
        unsigned short hu[4], lu[4];
        float k2s = 0.f;
        #pragma unroll
        for (int e = 0; e < 4; ++e) {
            float f = fb[e];
            k2s += f*f;
            hu[e] = f2bf(f);
            lu[e] = f2bf(f - bf2f(hu[e]));
            Vl[(lane16*4 + e)*66 + kl] = f2bf(vb[e]);
        }
        k2s += __shfl_xor(k2s, 1);
        k2s += __shfl_xor(k2s, 2);
        k2s += __shfl_xor(k2s, 4);
        k2s += __shfl_xor(k2s, 8);
        if (lane16 == 0) k2G[bh*NN + c2*CK + kl] = k2s;
        const int pos = (kl*DD + lane16*4) ^ ((kl & 7) << 3);
        *(uint2*)&KhiG[kbase + pos] = make_uint2((unsigned)hu[0] | ((unsigned)hu[1] << 16),
                                                 (unsigned)hu[2] | ((unsigned)hu[3] << 16));
        *(uint2*)&KloG[kbase + pos] = make_uint2((unsigned)lu[0] | ((unsigned)lu[1] << 16),
                                                 (unsigned)lu[2] | ((unsigned)lu[3] << 16));
    }
    __syncthreads();
    const size_t vbase = ((size_t)bh*NCH + c2)*(DD*CK);
    #pragma unroll
    for (int i = 0; i < 4; ++i) {
        const int gi = tid + 256*i;
        const int d   = gi >> 4;
        const int kl4 = (gi & 15) * 4;
        unsigned short e0 = Vl[d*66 + kl4+0];
        unsigned short e1 = Vl[d*66 + kl4+1];
        unsigned short e2 = Vl[d*66 + kl4+2];
        unsigned short e3 = Vl[d*66 + kl4+3];
        const int pos = (d*CK + kl4) ^ ((d & 7) << 3);
        *(uint2*)&VtG[vbase + pos] = make_uint2((unsigned)e0 | ((unsigned)e1 << 16),
                                                (unsigned)e2 | ((unsigned)e3 << 16));
    }
}

// ---------------- main: flash online softmax, double-buffered DMA staging, reg-geo ----------------
__global__ __launch_bounds__(512, 4) void geo_attn_main(
    const float* __restrict__ Q, const float* __restrict__ GEO,
    const unsigned short* __restrict__ KhiG, const unsigned short* __restrict__ KloG,
    const unsigned short* __restrict__ VtG, const float* __restrict__ k2G,
    float* __restrict__ OUT)
{
    // XCD-bijective swizzle (512 % 8 == 0): each XCD gets 64 consecutive tiles
    // (b-major grouping -> geo + K/V image re-reads hit that XCD's L2)
    const int bid  = blockIdx.x;
    const int tile = (bid & 7) * 64 + (bid >> 3);
    const int qt = tile & 3;
    const int h  = (tile >> 2) & 7;
    const int b  = tile >> 5;
    const int bh = b*NH + h;
    const int tid = threadIdx.x;
    const int w    = tid >> 6;
    const int lane = tid & 63;
    const int g = lane >> 4;
    const int c = lane & 15;

    __shared__ unsigned short Khi[2][CK*DD];     // 2 x 8KB
    __shared__ unsigned short Klo[2][CK*DD];     // 2 x 8KB
    __shared__ unsigned short vT [2][CK*DD];     // 2 x 8KB
    __shared__ unsigned short Pld[MWAVES*16*CK]; // 16KB
    __shared__ float k2s[NN];                    // 2KB
    __shared__ float sRow[MWAVES][16];
    __shared__ float rowinv[MWAVES][16];

    if (tid < NN) k2s[tid] = k2G[(size_t)bh*NN + tid];

    const int qb = qt*MQBLK + w*16;

    // Q fragments (hi/lo split) + q2
    bf16x8 qhi[2], qlo[2];
    float q2v = 0.f;
    {
        const float* qrow = Q + ((size_t)((b*NN + qb + c)*NH + h))*DD;
        #pragma unroll
        for (int dc = 0; dc < 2; ++dc) {
            float buf[8];
            *(float4*)&buf[0] = *(const float4*)(qrow + dc*32 + g*8);
            *(float4*)&buf[4] = *(const float4*)(qrow + dc*32 + g*8 + 4);
            #pragma unroll
            for (int i = 0; i < 8; ++i) {
                float f = buf[i];
                q2v += f*f;
                unsigned short hu = f2bf(f);
                qhi[dc][i] = (short)hu;
                qlo[dc][i] = (short)f2bf(f - bf2f(hu));
            }
        }
    }
    q2v += __shfl_xor(q2v, 16);
    q2v += __shfl_xor(q2v, 32);
    float nq2[4];
    #pragma unroll
    for (int r = 0; r < 4; ++r) nq2[r] = -8.f * __shfl(q2v, g*4 + r);

    f32x4 oacc[4];
    #pragma unroll
    for (int cb = 0; cb < 4; ++cb) { oacc[cb][0]=0.f; oacc[cb][1]=0.f; oacc[cb][2]=0.f; oacc[cb][3]=0.f; }
    float m_r[4] = {-3e38f, -3e38f, -3e38f, -3e38f};
    float l_r[4] = {0.f, 0.f, 0.f, 0.f};

    const char* gKhiB = (const char*)KhiG + (size_t)bh*(NN*DD*2);
    const char* gKloB = (const char*)KloG + (size_t)bh*(NN*DD*2);
    const char* gVtB  = (const char*)VtG  + (size_t)bh*(NN*DD*2);

    // each wave stages 1KB of each 8KB image chunk
    auto stage = [&](int buf, int ch2) {
        const int off = w*1024 + (lane<<4);
        gload16(gKhiB + ch2*(CK*DD*2) + off, (char*)&Khi[buf][0] + w*1024);
        gload16(gKloB + ch2*(CK*DD*2) + off, (char*)&Klo[buf][0] + w*1024);
        gload16(gVtB  + ch2*(CK*DD*2) + off, (char*)&vT [buf][0] + w*1024);
    };

    stage(0, 0);
    __syncthreads();   // chunk 0 staged (vmcnt drained) + k2s visible

    for (int ch = 0; ch < NCH; ++ch) {
        const int cur = ch & 1;
        if (ch + 1 < NCH) stage(cur ^ 1, ch + 1);   // prefetch next chunk

        // geo tile straight to registers (latency hides under QK MFMAs)
        float greg[16];
        {
            const float* gb2 = GEO + (size_t)b*NN*NN + (size_t)(qb + 4*g)*NN + ch*CK + c;
            #pragma unroll
            for (int tl = 0; tl < TL; ++tl)
                #pragma unroll
                for (int r = 0; r < 4; ++r)
                    greg[tl*4+r] = gb2[(size_t)r*NN + tl*16];
        }

        // QK^T (split bf16: 3 MFMAs per subtile)
        f32x4 sacc[TL];
        #pragma unroll
        for (int tl = 0; tl < TL; ++tl) { sacc[tl][0]=0.f; sacc[tl][1]=0.f; sacc[tl][2]=0.f; sacc[tl][3]=0.f; }
        __builtin_amdgcn_s_setprio(1);
        #pragma unroll
        for (int tl = 0; tl < TL; ++tl) {
            const int key = tl*16 + c;
            #pragma unroll
            for (int dc = 0; dc < 2; ++dc) {
                const int idx = (key*DD + dc*32 + g*8) ^ ((key & 7) << 3);
                bf16x8 kh = *(const bf16x8*)&Khi[cur][idx];
                bf16x8 kl = *(const bf16x8*)&Klo[cur][idx];
                sacc[tl] = __builtin_amdgcn_mfma_f32_16x16x32_bf16(qhi[dc], kh, sacc[tl], 0,0,0);
                sacc[tl] = __builtin_amdgcn_mfma_f32_16x16x32_bf16(qlo[dc], kh, sacc[tl], 0,0,0);
                sacc[tl] = __builtin_amdgcn_mfma_f32_16x16x32_bf16(qhi[dc], kl, sacc[tl], 0,0,0);
            }
        }
        __builtin_amdgcn_s_setprio(0);

        // logits + online softmax update
        float cmax[4] = {-3e38f, -3e38f, -3e38f, -3e38f};
        #pragma unroll
        for (int tl = 0; tl < TL; ++tl) {
            const float kk8 = -8.f * k2s[ch*CK + tl*16 + c];
            #pragma unroll
            for (int r = 0; r < 4; ++r) {
                float s = fmaf(16.f, sacc[tl][r], fmaf(8.f, greg[tl*4+r], nq2[r] + kk8));
                sacc[tl][r] = s;
                cmax[r] = fmaxf(cmax[r], s);
            }
        }
        float fac[4];
        #pragma unroll
        for (int r = 0; r < 4; ++r) {
            float mv = cmax[r];
            mv = fmaxf(mv, __shfl_xor(mv, 1));
            mv = fmaxf(mv, __shfl_xor(mv, 2));
            mv = fmaxf(mv, __shfl_xor(mv, 4));
            mv = fmaxf(mv, __shfl_xor(mv, 8));
            const float mnew = fmaxf(m_r[r], mv);
            fac[r] = __expf(m_r[r] - mnew);
            m_r[r] = mnew;
        }
        if (c == 0) {
            #pragma unroll
            for (int r = 0; r < 4; ++r) sRow[w][4*g + r] = fac[r];
        }
        #pragma unroll
        for (int r = 0; r < 4; ++r) l_r[r] *= fac[r];
        #pragma unroll
        for (int tl = 0; tl < TL; ++tl) {
            #pragma unroll
            for (int r = 0; r < 4; ++r) {
                float p = __expf(sacc[tl][r] - m_r[r]);
                l_r[r] += p;
                const int qloc = 4*g + r;
                Pld[(((w*16 + qloc)*CK) + tl*16 + c) ^ ((qloc & 7) << 3)] = f2bf(p);
            }
        }
        __syncthreads();   // P + sRow visible (prefetch already latency-covered)

        // PV accumulate (swapped: out^T = V^T * P^T)
        const float sc = sRow[w][c];
        #pragma unroll
        for (int cb = 0; cb < 4; ++cb) {
            oacc[cb][0] *= sc; oacc[cb][1] *= sc; oacc[cb][2] *= sc; oacc[cb][3] *= sc;
        }
        __builtin_amdgcn_s_setprio(1);
        #pragma unroll
        for (int kc = 0; kc < 2; ++kc) {
            bf16x8 pf = *(const bf16x8*)&Pld[(((w*16 + c)*CK) + kc*32 + g*8) ^ ((c & 7) << 3)];
            #pragma unroll
            for (int cb = 0; cb < 4; ++cb) {
                const int d = cb*16 + c;
                bf16x8 vfr = *(const bf16x8*)&vT[cur][(d*CK + kc*32 + g*8) ^ ((d & 7) << 3)];
                oacc[cb] = __builtin_amdgcn_mfma_f32_16x16x32_bf16(vfr, pf, oacc[cb], 0,0,0);
            }
        }
        __builtin_amdgcn_s_setprio(0);
        __syncthreads();   // buf[cur] + Pld free for next iteration
    }

    // epilogue: normalize + store
    #pragma unroll
    for (int r = 0; r < 4; ++r) {
        float sv = l_r[r];
        sv += __shfl_xor(sv, 1);
        sv += __shfl_xor(sv, 2);
        sv += __shfl_xor(sv, 4);
        sv += __shfl_xor(sv, 8);
        if (c == 0) rowinv[w][4*g + r] = 1.f / sv;
    }
    __syncthreads();
    const float inv = rowinv[w][c];
    float* orow = OUT + ((size_t)((b*NN + qb + c)*NH + h))*DD + 4*g;
    #pragma unroll
    for (int cb = 0; cb < 4; ++cb) {
        float4 ov;
        ov.x = oacc[cb][0] * inv;
        ov.y = oacc[cb][1] * inv;
        ov.z = oacc[cb][2] * inv;
        ov.w = oacc[cb][3] * inv;
        *(float4*)(orow + cb*16) = ov;
    }
}

// ---------------- fallback (round-1 kernel, used if ws too small) ----------------
__global__ __launch_bounds__(256, 2) void geo_attn_fallback(
    const float* __restrict__ Q, const float* __restrict__ K,
    const float* __restrict__ V, const float* __restrict__ GEO,
    float* __restrict__ OUT)
{
    const int qt  = blockIdx.x;
    const int h   = blockIdx.y;
    const int b   = blockIdx.z;
    const int tid = threadIdx.x;
    const int w    = tid >> 6;
    const int lane = tid & 63;
    const int g = lane >> 4;
    const int c = lane & 15;

    __shared__ unsigned short smemA[16384];
    __shared__ float k2p[2][NN];
    __shared__ float rowinvF[WAVES][16];

    unsigned short* KhiF = smemA;
    unsigned short* KloF = smemA + KBLK*DD;
    unsigned short* vTF  = smemA;
    unsigned short* PldF = smemA + DD*KBLK + w*16*KBLK;

    const int qb = qt*QBLK + w*16;

    bf16x8 qhi[2], qlo[2];
    float q2v = 0.f;
    {
        const float* qrow = Q + ((size_t)((b*NN + qb + c)*NH + h))*DD;
        #pragma unroll
        for (int dc = 0; dc < 2; ++dc) {
            float buf[8];
            *(float4*)&buf[0] = *(const float4*)(qrow + dc*32 + g*8);
            *(float4*)&buf[4] = *(const float4*)(qrow + dc*32 + g*8 + 4);
            #pragma unroll
            for (int i = 0; i < 8; ++i) {
                float f = buf[i];
                q2v += f*f;
                unsigned short hu = f2bf(f);
                qhi[dc][i] = (short)hu;
                qlo[dc][i] = (short)f2bf(f - bf2f(hu));
            }
        }
    }
    q2v += __shfl_xor(q2v, 16);
    q2v += __shfl_xor(q2v, 32);

    f32x4 zero4; zero4[0]=0.f; zero4[1]=0.f; zero4[2]=0.f; zero4[3]=0.f;
    f32x4 acc[NT];
    #pragma unroll
    for (int t = 0; t < NT; ++t) acc[t] = zero4;

    #pragma unroll
    for (int c2 = 0; c2 < NCHUNK; ++c2) {
        __syncthreads();
        {
            const int keyl = tid & (KBLK-1);
            const int half = tid >> 7;
            const int d0 = half*32;
            const float* krow = K + ((size_t)((b*NN + c2*KBLK + keyl)*NH + h))*DD + d0;
            float k2sv = 0.f;
            #pragma unroll
            for (int jj = 0; jj < 8; ++jj) {
                float4 f4 = *(const float4*)(krow + jj*4);
                float fb[4] = {f4.x, f4.y, f4.z, f4.w};
                unsigned short hu[4], lu[4];
                #pragma unroll
                for (int e = 0; e < 4; ++e) {
                    float f = fb[e];
                    k2sv += f*f;
                    hu[e] = f2bf(f);
                    lu[e] = f2bf(f - bf2f(hu[e]));
                }
                int idx = (keyl*DD + d0 + jj*4) ^ ((keyl & 7) << 3);
                *(uint2*)&KhiF[idx] = make_uint2((unsigned)hu[0] | ((unsigned)hu[1] << 16),
                                                 (unsigned)hu[2] | ((unsigned)hu[3] << 16));
                *(uint2*)&KloF[idx] = make_uint2((unsigned)lu[0] | ((unsigned)lu[1] << 16),
                                                 (unsigned)lu[2] | ((unsigned)lu[3] << 16));
            }
            k2p[half][c2*KBLK + keyl] = k2sv;
        }
        __syncthreads();
        #pragma unroll
        for (int tl = 0; tl < TPC; ++tl) {
            const int key = tl*16 + c;
            #pragma unroll
            for (int dc = 0; dc < 2; ++dc) {
                int idx = (key*DD + dc*32 + g*8) ^ ((key & 7) << 3);
                bf16x8 kh = *(const bf16x8*)&KhiF[idx];
                bf16x8 kl = *(const bf16x8*)&KloF[idx];
                acc[c2*TPC+tl] = __builtin_amdgcn_mfma_f32_16x16x32_bf16(qhi[dc], kh, acc[c2*TPC+tl], 0,0,0);
                acc[c2*TPC+tl] = __builtin_amdgcn_mfma_f32_16x16x32_bf16(qlo[dc], kh, acc[c2*TPC+tl], 0,0,0);
                acc[c2*TPC+tl] = __builtin_amdgcn_mfma_f32_16x16x32_bf16(qhi[dc], kl, acc[c2*TPC+tl], 0,0,0);
            }
        }
    }

    float nq2[4];
    #pragma unroll
    for (int r = 0; r < 4; ++r) nq2[r] = -8.f * __shfl(q2v, g*4 + r);

    const float* geoB = GEO + (size_t)b*NN*NN + (size_t)(qb + 4*g)*NN;

    float mx[4] = {-3e38f, -3e38f, -3e38f, -3e38f};
    #pragma unroll
    for (int t = 0; t < NT; ++t) {
        float kk8 = -8.f * (k2p[0][t*16 + c] + k2p[1][t*16 + c]);
        #pragma unroll
        for (int r = 0; r < 4; ++r) {
            float gv = geoB[(size_t)r*NN + t*16 + c];
            float s = fmaf(16.f, acc[t][r], fmaf(8.f, gv, nq2[r] + kk8));
            acc[t][r] = s;
            mx[r] = fmaxf(mx[r], s);
        }
    }
    #pragma unroll
    for (int r = 0; r < 4; ++r) {
        float mv = mx[r];
        mv = fmaxf(mv, __shfl_xor(mv, 1));
        mv = fmaxf(mv, __shfl_xor(mv, 2));
        mv = fmaxf(mv, __shfl_xor(mv, 4));
        mv = fmaxf(mv, __shfl_xor(mv, 8));
        mx[r] = mv;
    }
    float sm[4] = {0.f, 0.f, 0.f, 0.f};
    #pragma unroll
    for (int t = 0; t < NT; ++t) {
        #pragma unroll
        for (int r = 0; r < 4; ++r) {
            float p = __expf(acc[t][r] - mx[r]);
            acc[t][r] = p;
            sm[r] += p;
        }
    }
    #pragma unroll
    for (int r = 0; r < 4; ++r) {
        float sv = sm[r];
        sv += __shfl_xor(sv, 1);
        sv += __shfl_xor(sv, 2);
        sv += __shfl_xor(sv, 4);
        sv += __shfl_xor(sv, 8);
        sm[r] = sv;
    }
    if (c == 0) {
        #pragma unroll
        for (int r = 0; r < 4; ++r) rowinvF[w][4*g + r] = 1.f / sm[r];
    }

    f32x4 oacc[4];
    #pragma unroll
    for (int cb = 0; cb < 4; ++cb) oacc[cb] = zero4;

    #pragma unroll
    for (int c2 = 0; c2 < NCHUNK; ++c2) {
        __syncthreads();
        {
            const int keyl = tid & (KBLK-1);
            const int half = tid >> 7;
            const int d0 = half*32;
            const float* vrow = V + ((size_t)((b*NN + c2*KBLK + keyl)*NH + h))*DD + d0;
            #pragma unroll
            for (int jj = 0; jj < 8; ++jj) {
                float4 f4 = *(const float4*)(vrow + jj*4);
                float fb[4] = {f4.x, f4.y, f4.z, f4.w};
                #pragma unroll
                for (int e = 0; e < 4; ++e) {
                    int d = d0 + jj*4 + e;
                    vTF[(d*KBLK + keyl) ^ ((d & 7) << 3)] = f2bf(fb[e]);
                }
            }
        }
        #pragma unroll
        for (int tl = 0; tl < TPC; ++tl) {
            #pragma unroll
            for (int r = 0; r < 4; ++r) {
                int qloc = 4*g + r;
                PldF[(qloc*KBLK + tl*16 + c) ^ ((qloc & 7) << 3)] = f2bf(acc[c2*TPC+tl][r]);
            }
        }
        __syncthreads();
        #pragma unroll
        for (int kc = 0; kc < 4; ++kc) {
            int kb2 = kc*32 + g*8;
            bf16x8 pf = *(const bf16x8*)&PldF[(c*KBLK + kb2) ^ ((c & 7) << 3)];
            #pragma unroll
            for (int cb = 0; cb < 4; ++cb) {
                int d = cb*16 + c;
                bf16x8 vf = *(const bf16x8*)&vTF[(d*KBLK + kb2) ^ ((d & 7) << 3)];
                oacc[cb] = __builtin_amdgcn_mfma_f32_16x16x32_bf16(vf, pf, oacc[cb], 0,0,0);
            }
        }
    }

    const float inv = rowinvF[w][c];
    float* orow = OUT + ((size_t)((b*NN + qb + c)*NH + h))*DD + 4*g;
    #pragma unroll
    for (int cb = 0; cb < 4; ++cb) {
        float4 ov;
        ov.x = oacc[cb][0] * inv;
        ov.y = oacc[cb][1] * inv;
        ov.z = oacc[cb][2] * inv;
        ov.w = oacc[cb][3] * inv;
        *(float4*)(orow + cb*16) = ov;
    }
}

extern "C" void kernel_launch(void* const* d_in, const int* in_sizes, int n_in,
                              void* d_out, int out_size, void* d_ws, size_t ws_size,
                              hipStream_t stream) {
    const float* q   = (const float*)d_in[0];
    const float* k   = (const float*)d_in[1];
    const float* v   = (const float*)d_in[2];
    const float* geo = (const float*)d_in[3];
    float* out = (float*)d_out;

    const size_t IMG = (size_t)BB*NH*NN*DD*2;   // 8,388,608 B per bf16 image
    const size_t need = 3*IMG + (size_t)BB*NH*NN*4;

    if (ws_size >= need) {
        unsigned short* KhiG = (unsigned short*)d_ws;
        unsigned short* KloG = (unsigned short*)((char*)d_ws + IMG);
        unsigned short* VtG  = (unsigned short*)((char*)d_ws + 2*IMG);
        float*          k2G  = (float*)((char*)d_ws + 3*IMG);
        dim3 pgrid(NCH, NH, BB);
        geo_prep<<<pgrid, 256, 0, stream>>>(k, v, KhiG, KloG, VtG, k2G);
        geo_attn_main<<<dim3(512), 512, 0, stream>>>(q, geo, KhiG, KloG, VtG, k2G, out);
    } else {
        dim3 grid(NN/QBLK, NH, BB);
        geo_attn_fallback<<<grid, 256, 0, stream>>>(q, k, v, geo, out);
    }
}

// Round 4
// 132.846 us; speedup vs baseline: 1.1963x; 1.0847x over previous
//
#include <hip/hip_runtime.h>
#include <hip/hip_bf16.h>

#define BB 16
#define NN 512
#define NH 8
#define DD 64
#define CK 64        // keys per chunk
#define NCH 8        // NN / CK
#define TL 4         // 16-key tiles per chunk
// main kernel
#define MWAVES 8
#define MQBLK 128    // q rows per block (8 waves x 16)
// fallback kernel (round-1)
#define QBLK 64
#define WAVES 4
#define KBLK 128
#define NCHUNK 4
#define NT 32
#define TPC 8

typedef __attribute__((ext_vector_type(8))) short bf16x8;
typedef __attribute__((ext_vector_type(4))) float f32x4;

__device__ __forceinline__ unsigned short f2bf(float f) {
    unsigned int u = __float_as_uint(f);
    u += 0x7fffu + ((u >> 16) & 1u);     // round-to-nearest-even
    return (unsigned short)(u >> 16);
}
__device__ __forceinline__ float bf2f(unsigned short h) {
    return __uint_as_float(((unsigned int)h) << 16);
}
// packed f32x2 -> bf16x2 (RNE), one instruction
__device__ __forceinline__ unsigned int cvtpk(float a, float b) {
    unsigned int r;
    asm("v_cvt_pk_bf16_f32 %0, %1, %2" : "=v"(r) : "v"(a), "v"(b));
    return r;
}
// async global->LDS, 16B per lane; LDS dest = wave-uniform base + lane*16
__device__ __forceinline__ void gload16(const void* gsrc, void* lds) {
    __builtin_amdgcn_global_load_lds(
        (const __attribute__((address_space(1))) unsigned int*)gsrc,
        (__attribute__((address_space(3))) unsigned int*)lds, 16, 0, 0);
}

// ---------------- prep: K -> (hi,lo) bf16 swizzled images, V -> V^T bf16 swizzled image, k2n = -8*k2 ----------------
__global__ __launch_bounds__(256) void geo_prep(
    const float* __restrict__ K, const float* __restrict__ V,
    unsigned short* __restrict__ KhiG, unsigned short* __restrict__ KloG,
    unsigned short* __restrict__ VtG, float* __restrict__ k2G)
{
    const int c2 = blockIdx.x;   // 0..7 key chunk
    const int h  = blockIdx.y;
    const int b  = blockIdx.z;
    const int bh = b*NH + h;
    const int tid = threadIdx.x;
    const int lane16 = tid & 15;
    const int grp    = tid >> 4;   // 0..15

    __shared__ unsigned short Vl[DD*66];

    const size_t kbase = (size_t)bh*(NN*DD) + (size_t)c2*(CK*DD);
    #pragma unroll
    for (int kk = 0; kk < 4; ++kk) {
        const int kl = kk*16 + grp;
        const float* krow = K + ((size_t)(((b*NN + c2*CK + kl)*NH) + h))*DD + lane16*4;
        const float* vrow = V + ((size_t)(((b*NN + c2*CK + kl)*NH) + h))*DD + lane16*4;
        float4 kf = *(const float4*)krow;
        float4 vf = *(const float4*)vrow;
        float fb[4] = {kf.x, kf.y, kf.z, kf.w};
        float vb[4] = {vf.x, vf.y, vf.z, vf.w};
        unsigned short hu[4], lu[4];
        float k2s = 0.f;
        #pragma unroll
        for (int e = 0; e < 4; ++e) {
            float f = fb[e];
            k2s += f*f;
            hu[e] = f2bf(f);
            lu[e] = f2bf(f - bf2f(hu[e]));
            Vl[(lane16*4 + e)*66 + kl] = f2bf(vb[e]);
        }
        k2s += __shfl_xor(k2s, 1);
        k2s += __shfl_xor(k2s, 2);
        k2s += __shfl_xor(k2s, 4);
        k2s += __shfl_xor(k2s, 8);
        if (lane16 == 0) k2G[bh*NN + c2*CK + kl] = -8.f * k2s;   // pre-scaled
        const int pos = (kl*DD + lane16*4) ^ ((kl & 7) << 3);
        *(uint2*)&KhiG[kbase + pos] = make_uint2((unsigned)hu[0] | ((unsigned)hu[1] << 16),
                                                 (unsigned)hu[2] | ((unsigned)hu[3] << 16));
        *(uint2*)&KloG[kbase + pos] = make_uint2((unsigned)lu[0] | ((unsigned)lu[1] << 16),
                                                 (unsigned)lu[2] | ((unsigned)lu[3] << 16));
    }
    __syncthreads();
    const size_t vbase = ((size_t)bh*NCH + c2)*(DD*CK);
    #pragma unroll
    for (int i = 0; i < 4; ++i) {
        const int gi = tid + 256*i;
        const int d   = gi >> 4;
        const int kl4 = (gi & 15) * 4;
        unsigned short e0 = Vl[d*66 + kl4+0];
        unsigned short e1 = Vl[d*66 + kl4+1];
        unsigned short e2 = Vl[d*66 + kl4+2];
        unsigned short e3 = Vl[d*66 + kl4+3];
        const int pos = (d*CK + kl4) ^ ((d & 7) << 3);
        *(uint2*)&VtG[vbase + pos] = make_uint2((unsigned)e0 | ((unsigned)e1 << 16),
                                                (unsigned)e2 | ((unsigned)e3 << 16));
    }
}

// ---------------- main: swapped QK^T (S^T), lane-local softmax, 1 barrier/chunk ----------------
__global__ __launch_bounds__(512, 4) void geo_attn_main(
    const float* __restrict__ Q, const float* __restrict__ GEO,
    const unsigned short* __restrict__ KhiG, const unsigned short* __restrict__ KloG,
    const unsigned short* __restrict__ VtG, const float* __restrict__ k2G,
    float* __restrict__ OUT)
{
    // XCD-bijective swizzle (512 % 8 == 0): b-major grouping per XCD
    const int bid  = blockIdx.x;
    const int tile = (bid & 7) * 64 + (bid >> 3);
    const int qt = tile & 3;
    const int h  = (tile >> 2) & 7;
    const int b  = tile >> 5;
    const int bh = b*NH + h;
    const int tid = threadIdx.x;
    const int w    = tid >> 6;
    const int lane = tid & 63;
    const int g = lane >> 4;
    const int c = lane & 15;

    __shared__ unsigned short Khi[2][CK*DD];     // 2 x 8KB
    __shared__ unsigned short Klo[2][CK*DD];     // 2 x 8KB
    __shared__ unsigned short vT [2][CK*DD];     // 2 x 8KB
    __shared__ unsigned short Pld[MWAVES*16*CK]; // 16KB (wave-private sections)
    __shared__ float k2n[NN];                    // 2KB, holds -8*k2

    if (tid < NN) k2n[tid] = k2G[(size_t)bh*NN + tid];

    const int qb = qt*MQBLK + w*16;

    // Q fragments (hi/lo split); q^2 dropped: softmax is shift-invariant per row
    bf16x8 qhi[2], qlo[2];
    {
        const float* qrow = Q + ((size_t)((b*NN + qb + c)*NH + h))*DD;
        #pragma unroll
        for (int dc = 0; dc < 2; ++dc) {
            float buf[8];
            *(float4*)&buf[0] = *(const float4*)(qrow + dc*32 + g*8);
            *(float4*)&buf[4] = *(const float4*)(qrow + dc*32 + g*8 + 4);
            #pragma unroll
            for (int i = 0; i < 8; ++i) {
                float f = buf[i];
                unsigned short hu = f2bf(f);
                qhi[dc][i] = (short)hu;
                qlo[dc][i] = (short)f2bf(f - bf2f(hu));
            }
        }
    }

    f32x4 oacc[4];
    #pragma unroll
    for (int cb = 0; cb < 4; ++cb) { oacc[cb][0]=0.f; oacc[cb][1]=0.f; oacc[cb][2]=0.f; oacc[cb][3]=0.f; }
    float m_run = -3e38f;
    float l_run = 0.f;

    const char* gKhiB = (const char*)KhiG + (size_t)bh*(NN*DD*2);
    const char* gKloB = (const char*)KloG + (size_t)bh*(NN*DD*2);
    const char* gVtB  = (const char*)VtG  + (size_t)bh*(NN*DD*2);
    const float* geoR = GEO + (size_t)b*NN*NN + (size_t)(qb + c)*NN;   // this lane's q-row

    auto stage = [&](int buf, int ch2) {
        const int off = w*1024 + (lane<<4);
        gload16(gKhiB + ch2*(CK*DD*2) + off, (char*)&Khi[buf][0] + w*1024);
        gload16(gKloB + ch2*(CK*DD*2) + off, (char*)&Klo[buf][0] + w*1024);
        gload16(gVtB  + ch2*(CK*DD*2) + off, (char*)&vT [buf][0] + w*1024);
    };

    stage(0, 0);
    __syncthreads();   // chunk 0 staged + k2n visible

    for (int ch = 0; ch < NCH; ++ch) {
        const int cur = ch & 1;

        // geo float4 loads ISSUED BEFORE stage -> vmcnt for logits leaves DMAs outstanding
        float4 gq[TL];
        #pragma unroll
        for (int tl = 0; tl < TL; ++tl)
            gq[tl] = *(const float4*)(geoR + ch*CK + tl*16 + 4*g);

        if (ch + 1 < NCH) stage(cur ^ 1, ch + 1);   // prefetch next chunk

        float4 kn[TL];
        #pragma unroll
        for (int tl = 0; tl < TL; ++tl)
            kn[tl] = *(const float4*)&k2n[ch*CK + tl*16 + 4*g];

        // QK^T swapped: A=K, B=Q  ->  sacc[tl][r] = S[q = qb+c][key = ch*64+16tl+4g+r]
        f32x4 sacc[TL];
        #pragma unroll
        for (int tl = 0; tl < TL; ++tl) { sacc[tl][0]=0.f; sacc[tl][1]=0.f; sacc[tl][2]=0.f; sacc[tl][3]=0.f; }
        __builtin_amdgcn_s_setprio(1);
        #pragma unroll
        for (int tl = 0; tl < TL; ++tl) {
            const int key = tl*16 + c;
            #pragma unroll
            for (int dc = 0; dc < 2; ++dc) {
                const int idx = (key*DD + dc*32 + g*8) ^ ((key & 7) << 3);
                bf16x8 kh = *(const bf16x8*)&Khi[cur][idx];
                bf16x8 kl = *(const bf16x8*)&Klo[cur][idx];
                sacc[tl] = __builtin_amdgcn_mfma_f32_16x16x32_bf16(kh, qhi[dc], sacc[tl], 0,0,0);
                sacc[tl] = __builtin_amdgcn_mfma_f32_16x16x32_bf16(kh, qlo[dc], sacc[tl], 0,0,0);
                sacc[tl] = __builtin_amdgcn_mfma_f32_16x16x32_bf16(kl, qhi[dc], sacc[tl], 0,0,0);
            }
        }
        __builtin_amdgcn_s_setprio(0);

        // logits: s = 16*qk + 8*geo - 8*k2  (q2 term dropped); lane-local row max
        float p[16];
        float cmax = -3e38f;
        #pragma unroll
        for (int tl = 0; tl < TL; ++tl) {
            const float ge[4] = {gq[tl].x, gq[tl].y, gq[tl].z, gq[tl].w};
            const float ke[4] = {kn[tl].x, kn[tl].y, kn[tl].z, kn[tl].w};
            #pragma unroll
            for (int r = 0; r < 4; ++r) {
                float s = fmaf(16.f, sacc[tl][r], fmaf(8.f, ge[r], ke[r]));
                p[tl*4+r] = s;
                cmax = fmaxf(cmax, s);
            }
        }
        // other 48 keys of this q-row live on the g-replica lanes: 2 shuffles
        cmax = fmaxf(cmax, __shfl_xor(cmax, 16));
        cmax = fmaxf(cmax, __shfl_xor(cmax, 32));
        const float mnew = fmaxf(m_run, cmax);
        const float fac = __expf(m_run - mnew);
        m_run = mnew;
        float cs = 0.f;
        #pragma unroll
        for (int i = 0; i < 16; ++i) { p[i] = __expf(p[i] - mnew); cs += p[i]; }
        cs += __shfl_xor(cs, 16);
        cs += __shfl_xor(cs, 32);
        l_run = fmaf(l_run, fac, cs);

        // pack P -> own wave's Pld row (q=c), cols 16tl+4g..+3 (b64 writes)
        #pragma unroll
        for (int tl = 0; tl < TL; ++tl) {
            unsigned int u0 = cvtpk(p[tl*4+0], p[tl*4+1]);
            unsigned int u1 = cvtpk(p[tl*4+2], p[tl*4+3]);
            const int idx = (((w*16 + c)*CK) + tl*16 + 4*g) ^ ((c & 7) << 3);
            *(uint2*)&Pld[idx] = make_uint2(u0, u1);
        }

        // PV accumulate (out^T = V^T * P^T); fac is lane-local (q=c matches D col)
        #pragma unroll
        for (int cb = 0; cb < 4; ++cb) {
            oacc[cb][0] *= fac; oacc[cb][1] *= fac; oacc[cb][2] *= fac; oacc[cb][3] *= fac;
        }
        __builtin_amdgcn_s_setprio(1);
        #pragma unroll
        for (int kc = 0; kc < 2; ++kc) {
            bf16x8 pf = *(const bf16x8*)&Pld[(((w*16 + c)*CK) + kc*32 + g*8) ^ ((c & 7) << 3)];
            #pragma unroll
            for (int cb = 0; cb < 4; ++cb) {
                const int d = cb*16 + c;
                bf16x8 vfr = *(const bf16x8*)&vT[cur][(d*CK + kc*32 + g*8) ^ ((d & 7) << 3)];
                oacc[cb] = __builtin_amdgcn_mfma_f32_16x16x32_bf16(vfr, pf, oacc[cb], 0,0,0);
            }
        }
        __builtin_amdgcn_s_setprio(0);
        __syncthreads();   // all waves done with buf[cur]; next-chunk DMA drained
    }

    // epilogue: l_run replicated across g -> inv lane-local, no LDS round trip
    const float inv = 1.f / l_run;
    float* orow = OUT + ((size_t)((b*NN + qb + c)*NH + h))*DD + 4*g;
    #pragma unroll
    for (int cb = 0; cb < 4; ++cb) {
        float4 ov;
        ov.x = oacc[cb][0] * inv;
        ov.y = oacc[cb][1] * inv;
        ov.z = oacc[cb][2] * inv;
        ov.w = oacc[cb][3] * inv;
        *(float4*)(orow + cb*16) = ov;
    }
}

// ---------------- fallback (round-1 kernel, used if ws too small) ----------------
__global__ __launch_bounds__(256, 2) void geo_attn_fallback(
    const float* __restrict__ Q, const float* __restrict__ K,
    const float* __restrict__ V, const float* __restrict__ GEO,
    float* __restrict__ OUT)
{
    const int qt  = blockIdx.x;
    const int h   = blockIdx.y;
    const int b   = blockIdx.z;
    const int tid = threadIdx.x;
    const int w    = tid >> 6;
    const int lane = tid & 63;
    const int g = lane >> 4;
    const int c = lane & 15;

    __shared__ unsigned short smemA[16384];
    __shared__ float k2p[2][NN];
    __shared__ float rowinvF[WAVES][16];

    unsigned short* KhiF = smemA;
    unsigned short* KloF = smemA + KBLK*DD;
    unsigned short* vTF  = smemA;
    unsigned short* PldF = smemA + DD*KBLK + w*16*KBLK;

    const int qb = qt*QBLK + w*16;

    bf16x8 qhi[2], qlo[2];
    float q2v = 0.f;
    {
        const float* qrow = Q + ((size_t)((b*NN + qb + c)*NH + h))*DD;
        #pragma unroll
        for (int dc = 0; dc < 2; ++dc) {
            float buf[8];
            *(float4*)&buf[0] = *(const float4*)(qrow + dc*32 + g*8);
            *(float4*)&buf[4] = *(const float4*)(qrow + dc*32 + g*8 + 4);
            #pragma unroll
            for (int i = 0; i < 8; ++i) {
                float f = buf[i];
                q2v += f*f;
                unsigned short hu = f2bf(f);
                qhi[dc][i] = (short)hu;
                qlo[dc][i] = (short)f2bf(f - bf2f(hu));
            }
        }
    }
    q2v += __shfl_xor(q2v, 16);
    q2v += __shfl_xor(q2v, 32);

    f32x4 zero4; zero4[0]=0.f; zero4[1]=0.f; zero4[2]=0.f; zero4[3]=0.f;
    f32x4 acc[NT];
    #pragma unroll
    for (int t = 0; t < NT; ++t) acc[t] = zero4;

    #pragma unroll
    for (int c2 = 0; c2 < NCHUNK; ++c2) {
        __syncthreads();
        {
            const int keyl = tid & (KBLK-1);
            const int half = tid >> 7;
            const int d0 = half*32;
            const float* krow = K + ((size_t)((b*NN + c2*KBLK + keyl)*NH + h))*DD + d0;
            float k2sv = 0.f;
            #pragma unroll
            for (int jj = 0; jj < 8; ++jj) {
                float4 f4 = *(const float4*)(krow + jj*4);
                float fb[4] = {f4.x, f4.y, f4.z, f4.w};
                unsigned short hu[4], lu[4];
                #pragma unroll
                for (int e = 0; e < 4; ++e) {
                    float f = fb[e];
                    k2sv += f*f;
                    hu[e] = f2bf(f);
                    lu[e] = f2bf(f - bf2f(hu[e]));
                }
                int idx = (keyl*DD + d0 + jj*4) ^ ((keyl & 7) << 3);
                *(uint2*)&KhiF[idx] = make_uint2((unsigned)hu[0] | ((unsigned)hu[1] << 16),
                                                 (unsigned)hu[2] | ((unsigned)hu[3] << 16));
                *(uint2*)&KloF[idx] = make_uint2((unsigned)lu[0] | ((unsigned)lu[1] << 16),
                                                 (unsigned)lu[2] | ((unsigned)lu[3] << 16));
            }
            k2p[half][c2*KBLK + keyl] = k2sv;
        }
        __syncthreads();
        #pragma unroll
        for (int tl = 0; tl < TPC; ++tl) {
            const int key = tl*16 + c;
            #pragma unroll
            for (int dc = 0; dc < 2; ++dc) {
                int idx = (key*DD + dc*32 + g*8) ^ ((key & 7) << 3);
                bf16x8 kh = *(const bf16x8*)&KhiF[idx];
                bf16x8 kl = *(const bf16x8*)&KloF[idx];
                acc[c2*TPC+tl] = __builtin_amdgcn_mfma_f32_16x16x32_bf16(qhi[dc], kh, acc[c2*TPC+tl], 0,0,0);
                acc[c2*TPC+tl] = __builtin_amdgcn_mfma_f32_16x16x32_bf16(qlo[dc], kh, acc[c2*TPC+tl], 0,0,0);
                acc[c2*TPC+tl] = __builtin_amdgcn_mfma_f32_16x16x32_bf16(qhi[dc], kl, acc[c2*TPC+tl], 0,0,0);
            }
        }
    }

    float nq2[4];
    #pragma unroll
    for (int r = 0; r < 4; ++r) nq2[r] = -8.f * __shfl(q2v, g*4 + r);

    const float* geoB = GEO + (size_t)b*NN*NN + (size_t)(qb + 4*g)*NN;

    float mx[4] = {-3e38f, -3e38f, -3e38f, -3e38f};
    #pragma unroll
    for (int t = 0; t < NT; ++t) {
        float kk8 = -8.f * (k2p[0][t*16 + c] + k2p[1][t*16 + c]);
        #pragma unroll
        for (int r = 0; r < 4; ++r) {
            float gv = geoB[(size_t)r*NN + t*16 + c];
            float s = fmaf(16.f, acc[t][r], fmaf(8.f, gv, nq2[r] + kk8));
            acc[t][r] = s;
            mx[r] = fmaxf(mx[r], s);
        }
    }
    #pragma unroll
    for (int r = 0; r < 4; ++r) {
        float mv = mx[r];
        mv = fmaxf(mv, __shfl_xor(mv, 1));
        mv = fmaxf(mv, __shfl_xor(mv, 2));
        mv = fmaxf(mv, __shfl_xor(mv, 4));
        mv = fmaxf(mv, __shfl_xor(mv, 8));
        mx[r] = mv;
    }
    float sm[4] = {0.f, 0.f, 0.f, 0.f};
    #pragma unroll
    for (int t = 0; t < NT; ++t) {
        #pragma unroll
        for (int r = 0; r < 4; ++r) {
            float p = __expf(acc[t][r] - mx[r]);
            acc[t][r] = p;
            sm[r] += p;
        }
    }
    #pragma unroll
    for (int r = 0; r < 4; ++r) {
        float sv = sm[r];
        sv += __shfl_xor(sv, 1);
        sv += __shfl_xor(sv, 2);
        sv += __shfl_xor(sv, 4);
        sv += __shfl_xor(sv, 8);
        sm[r] = sv;
    }
    if (c == 0) {
        #pragma unroll
        for (int r = 0; r < 4; ++r) rowinvF[w][4*g + r] = 1.f / sm[r];
    }

    f32x4 oacc[4];
    #pragma unroll
    for (int cb = 0; cb < 4; ++cb) oacc[cb] = zero4;

    #pragma unroll
    for (int c2 = 0; c2 < NCHUNK; ++c2) {
        __syncthreads();
        {
            const int keyl = tid & (KBLK-1);
            const int half = tid >> 7;
            const int d0 = half*32;
            const float* vrow = V + ((size_t)((b*NN + c2*KBLK + keyl)*NH + h))*DD + d0;
            #pragma unroll
            for (int jj = 0; jj < 8; ++jj) {
                float4 f4 = *(const float4*)(vrow + jj*4);
                float fb[4] = {f4.x, f4.y, f4.z, f4.w};
                #pragma unroll
                for (int e = 0; e < 4; ++e) {
                    int d = d0 + jj*4 + e;
                    vTF[(d*KBLK + keyl) ^ ((d & 7) << 3)] = f2bf(fb[e]);
                }
            }
        }
        #pragma unroll
        for (int tl = 0; tl < TPC; ++tl) {
            #pragma unroll
            for (int r = 0; r < 4; ++r) {
                int qloc = 4*g + r;
                PldF[(qloc*KBLK + tl*16 + c) ^ ((qloc & 7) << 3)] = f2bf(acc[c2*TPC+tl][r]);
            }
        }
        __syncthreads();
        #pragma unroll
        for (int kc = 0; kc < 4; ++kc) {
            int kb2 = kc*32 + g*8;
            bf16x8 pf = *(const bf16x8*)&PldF[(c*KBLK + kb2) ^ ((c & 7) << 3)];
            #pragma unroll
            for (int cb = 0; cb < 4; ++cb) {
                int d = cb*16 + c;
                bf16x8 vf = *(const bf16x8*)&vTF[(d*KBLK + kb2) ^ ((d & 7) << 3)];
                oacc[cb] = __builtin_amdgcn_mfma_f32_16x16x32_bf16(vf, pf, oacc[cb], 0,0,0);
            }
        }
    }

    const float inv = rowinvF[w][c];
    float* orow = OUT + ((size_t)((b*NN + qb + c)*NH + h))*DD + 4*g;
    #pragma unroll
    for (int cb = 0; cb < 4; ++cb) {
        float4 ov;
        ov.x = oacc[cb][0] * inv;
        ov.y = oacc[cb][1] * inv;
        ov.z = oacc[cb][2] * inv;
        ov.w = oacc[cb][3] * inv;
        *(float4*)(orow + cb*16) = ov;
    }
}

extern "C" void kernel_launch(void* const* d_in, const int* in_sizes, int n_in,
                              void* d_out, int out_size, void* d_ws, size_t ws_size,
                              hipStream_t stream) {
    const float* q   = (const float*)d_in[0];
    const float* k   = (const float*)d_in[1];
    const float* v   = (const float*)d_in[2];
    const float* geo = (const float*)d_in[3];
    float* out = (float*)d_out;

    const size_t IMG = (size_t)BB*NH*NN*DD*2;   // 8,388,608 B per bf16 image
    const size_t need = 3*IMG + (size_t)BB*NH*NN*4;

    if (ws_size >= need) {
        unsigned short* KhiG = (unsigned short*)d_ws;
        unsigned short* KloG = (unsigned short*)((char*)d_ws + IMG);
        unsigned short* VtG  = (unsigned short*)((char*)d_ws + 2*IMG);
        float*          k2G  = (float*)((char*)d_ws + 3*IMG);
        dim3 pgrid(NCH, NH, BB);
        geo_prep<<<pgrid, 256, 0, stream>>>(k, v, KhiG, KloG, VtG, k2G);
        geo_attn_main<<<dim3(512), 512, 0, stream>>>(q, geo, KhiG, KloG, VtG, k2G, out);
    } else {
        dim3 grid(NN/QBLK, NH, BB);
        geo_attn_fallback<<<grid, 256, 0, stream>>>(q, k, v, geo, out);
    }
}